// Round 9
// baseline (272.220 us; speedup 1.0000x reference)
//
#include <hip/hip_runtime.h>
#include <hip/hip_bf16.h>

// GroupEmbedding: out[g,d] = sum_u ( (sum_m item_emb[beh_ids[g,u,m],d]*cnt[g,u,m])
//                                    * user_emb[group_user[g,u],d]
//                                    * 0.5*dot(sim[target[g]], sim[group_user[g,u]]) )
// G=4096, U=50, M=20, D=S=64.
//
// R8 post-mortem: narrow-gather (151us, VALU 28%) and wide-gather (157us,
// VALU 11%) both pin at ~3.3 TB/s L2-miss traffic -> NOT issue-bound.
// Remaining models: (a) random-line service-rate ceiling (structural) vs
// (b) latency x per-CU-concurrency bound. Discriminator: raise resident
// waves 22 -> 32 per CU via 128-thread blocks (16 wg/CU x 2 waves = 100%
// occupancy; whole grid resident). If (b): ~110-125us. If (a): unchanged.

constexpr int G = 4096;
constexpr int U = 50;
constexpr int M = 20;
constexpr int D = 64;
constexpr int S = 64;
constexpr int UPAD = 56;            // 7 iters * 2 waves * 4 subgroups
constexpr float FACTOR = 0.5f;

__global__ __launch_bounds__(128) void group_embedding_kernel(
    const int*   __restrict__ group_user,       // [G,U]
    const int*   __restrict__ behavior_ids,     // [G,U,M]
    const float* __restrict__ behavior_counts,  // [G,U,M]
    const int*   __restrict__ target_user,      // [G]
    const float* __restrict__ similarity_vec,   // [USER_NUM,S]
    const float* __restrict__ user_emb_w,       // [USER_NUM,D]
    const float* __restrict__ item_emb_w,       // [ITEM_NUM,D]
    float*       __restrict__ out)              // [G,D]
{
    const int g    = blockIdx.x;
    const int tid  = threadIdx.x;
    const int wave = tid >> 6;     // 0..1
    const int lane = tid & 63;
    const int uu   = lane >> 4;    // user subgroup 0..3
    const int q    = lane & 15;    // dim quad: dims 4q..4q+3

    __shared__ int    gu_lds[UPAD];
    __shared__ int    ids_lds[UPAD * M];
    __shared__ float  cnt_lds[UPAD * M];
    __shared__ float4 red[16];     // wave 1's partial

    // ---- stage ids/counts/group_user into LDS (coalesced), zero-pad u>=U ----
    for (int i = tid; i < UPAD * M; i += 128) {
        const bool v = (i < U * M);
        ids_lds[i] = v ? behavior_ids   [(size_t)g * U * M + i] : 0;
        cnt_lds[i] = v ? behavior_counts[(size_t)g * U * M + i] : 0.0f;
    }
    if (tid < UPAD) gu_lds[tid] = (tid < U) ? group_user[g * U + tid] : 0;
    __syncthreads();

    const int tgt = target_user[g];
    const float4 tsim = *(const float4*)(similarity_vec + (size_t)tgt * S + 4 * q);

    float4 acc = {0.f, 0.f, 0.f, 0.f};

    #pragma unroll 1
    for (int iter = 0; iter < UPAD / 8; ++iter) {   // 7 iterations
        const int u  = iter * 8 + wave * 4 + uu;    // 0..55, in-bounds
        const int gu = gu_lds[u];

        // --- sim weight: 0.5 * dot(sim[tgt], sim[gu]); one 1KB gather / 4 users
        const float4 sv = *(const float4*)(similarity_vec + (size_t)gu * S + 4 * q);
        float p = tsim.x * sv.x + tsim.y * sv.y + tsim.z * sv.z + tsim.w * sv.w;
        p += __shfl_xor(p, 1);
        p += __shfl_xor(p, 2);
        p += __shfl_xor(p, 4);
        p += __shfl_xor(p, 8);      // full 64-elem dot within the 16-lane group
        const float sim = FACTOR * p;

        // --- user embedding quad (1KB gather / 4 users)
        const float4 ue = *(const float4*)(user_emb_w + (size_t)gu * D + 4 * q);

        // --- weighted behavior sum: 20 gathers, each 4 rows x 16B = 1KB
        float4 ub = {0.f, 0.f, 0.f, 0.f};
        #pragma unroll
        for (int m = 0; m < M; ++m) {
            const int   id = ids_lds[u * M + m];   // LDS broadcast per group
            const float c  = cnt_lds[u * M + m];
            const float4 it = *(const float4*)(item_emb_w + (size_t)id * D + 4 * q);
            ub.x = fmaf(it.x, c, ub.x);
            ub.y = fmaf(it.y, c, ub.y);
            ub.z = fmaf(it.z, c, ub.z);
            ub.w = fmaf(it.w, c, ub.w);
        }

        acc.x = fmaf(ub.x * ue.x, sim, acc.x);
        acc.y = fmaf(ub.y * ue.y, sim, acc.y);
        acc.z = fmaf(ub.z * ue.z, sim, acc.z);
        acc.w = fmaf(ub.w * ue.w, sim, acc.w);
    }

    // ---- combine the 4 user-subgroups (stride-16/32 butterfly) ----
    #pragma unroll
    for (int off = 16; off < 64; off <<= 1) {
        acc.x += __shfl_xor(acc.x, off);
        acc.y += __shfl_xor(acc.y, off);
        acc.z += __shfl_xor(acc.z, off);
        acc.w += __shfl_xor(acc.w, off);
    }
    if (wave == 1 && uu == 0) red[q] = acc;
    __syncthreads();

    // ---- combine the 2 waves; 16 lanes store 256B coalesced ----
    if (wave == 0 && uu == 0) {
        const float4 r1 = red[q];
        float4 o;
        o.x = acc.x + r1.x;
        o.y = acc.y + r1.y;
        o.z = acc.z + r1.z;
        o.w = acc.w + r1.w;
        *(float4*)(out + (size_t)g * D + 4 * q) = o;
    }
}

extern "C" void kernel_launch(void* const* d_in, const int* in_sizes, int n_in,
                              void* d_out, int out_size, void* d_ws, size_t ws_size,
                              hipStream_t stream) {
    const int*   group_user      = (const int*)  d_in[0];
    const int*   behavior_ids    = (const int*)  d_in[1];
    const float* behavior_counts = (const float*)d_in[2];
    const int*   target_user     = (const int*)  d_in[3];
    const float* similarity_vec  = (const float*)d_in[4];
    const float* user_emb_w      = (const float*)d_in[5];
    const float* item_emb_w      = (const float*)d_in[6];
    float*       out             = (float*)d_out;

    group_embedding_kernel<<<G, 128, 0, stream>>>(
        group_user, behavior_ids, behavior_counts, target_user,
        similarity_vec, user_emb_w, item_emb_w, out);
}

// Round 10
// 261.118 us; speedup vs baseline: 1.0425x; 1.0425x over previous
//
#include <hip/hip_runtime.h>
#include <hip/hip_bf16.h>

// GroupEmbedding — G=4096, U=50, M=20, D=S=64.
// R9 post-mortem: VGPR=36 revealed ~2-4 outstanding lines/wave; BW scaled with
// wave count -> latency x MLP bound, NOT a service ceiling. This round: batch
// ALL 22 gathers of an iteration into registers before consuming (per-wave
// in-flight ~4 -> ~320 lines). Expect VGPR ~140, occupancy ~50%, dur 151->~90us.

constexpr int G = 4096;
constexpr int U = 50;
constexpr int M = 20;
constexpr int D = 64;
constexpr int S = 64;
constexpr int UPAD = 64;            // 4 waves * 4 subgroups * 4 iters
constexpr float FACTOR = 0.5f;

__global__ __launch_bounds__(256) void group_embedding_kernel(
    const int*   __restrict__ group_user,       // [G,U]
    const int*   __restrict__ behavior_ids,     // [G,U,M]
    const float* __restrict__ behavior_counts,  // [G,U,M]
    const int*   __restrict__ target_user,      // [G]
    const float* __restrict__ similarity_vec,   // [USER_NUM,S]
    const float* __restrict__ user_emb_w,       // [USER_NUM,D]
    const float* __restrict__ item_emb_w,       // [ITEM_NUM,D]
    float*       __restrict__ out)              // [G,D]
{
    const int g    = blockIdx.x;
    const int tid  = threadIdx.x;
    const int wave = tid >> 6;     // 0..3
    const int lane = tid & 63;
    const int uu   = lane >> 4;    // user subgroup 0..3
    const int q    = lane & 15;    // dim quad: dims 4q..4q+3

    __shared__ int    gu_lds[UPAD];
    __shared__ int    ids_lds[UPAD * M];
    __shared__ float  cnt_lds[UPAD * M];
    __shared__ float4 red[4][16];

    // ---- stage ids/counts/group_user into LDS (coalesced), zero-pad u>=U ----
    // (pad users: gu=0 -> user_emb row0 = 0; pad ids=0 with cnt=0 -> no effect)
    for (int i = tid; i < UPAD * M; i += 256) {
        const bool v = (i < U * M);
        ids_lds[i] = v ? behavior_ids   [(size_t)g * U * M + i] : 0;
        cnt_lds[i] = v ? behavior_counts[(size_t)g * U * M + i] : 0.0f;
    }
    if (tid < UPAD) gu_lds[tid] = (tid < U) ? group_user[g * U + tid] : 0;
    __syncthreads();

    const int tgt = target_user[g];
    const float4 tsim = *(const float4*)(similarity_vec + (size_t)tgt * S + 4 * q);

    float4 acc = {0.f, 0.f, 0.f, 0.f};

    #pragma unroll 1
    for (int iter = 0; iter < UPAD / 16; ++iter) {
        const int u  = iter * 16 + wave * 4 + uu;   // 0..63
        const int gu = gu_lds[u];

        // LDS reads up front (lgkm), so the VMEM issue burst is uninterrupted.
        int   ids [M];
        float cnts[M];
        #pragma unroll
        for (int m = 0; m < M; ++m) {
            ids [m] = ids_lds[u * M + m];
            cnts[m] = cnt_lds[u * M + m];
        }

        // ---- ISSUE all 22 gathers (each 4 rows x 16B = 16 lines in flight) ----
        const float4 sv = *(const float4*)(similarity_vec + (size_t)gu * S + 4 * q);
        const float4 ue = *(const float4*)(user_emb_w     + (size_t)gu * D + 4 * q);
        float4 it[M];                       // 80 VGPRs, compile-time indexed
        #pragma unroll
        for (int m = 0; m < M; ++m)
            it[m] = *(const float4*)(item_emb_w + (size_t)ids[m] * D + 4 * q);

        // ---- CONSUME: sim dot + shfl reduce overlaps in-flight item loads ----
        float p = tsim.x * sv.x + tsim.y * sv.y + tsim.z * sv.z + tsim.w * sv.w;
        p += __shfl_xor(p, 1);
        p += __shfl_xor(p, 2);
        p += __shfl_xor(p, 4);
        p += __shfl_xor(p, 8);      // 64-elem dot within the 16-lane group
        const float sim = FACTOR * p;

        float4 ub = {0.f, 0.f, 0.f, 0.f};
        #pragma unroll
        for (int m = 0; m < M; ++m) {
            ub.x = fmaf(it[m].x, cnts[m], ub.x);
            ub.y = fmaf(it[m].y, cnts[m], ub.y);
            ub.z = fmaf(it[m].z, cnts[m], ub.z);
            ub.w = fmaf(it[m].w, cnts[m], ub.w);
        }

        acc.x = fmaf(ub.x * ue.x, sim, acc.x);
        acc.y = fmaf(ub.y * ue.y, sim, acc.y);
        acc.z = fmaf(ub.z * ue.z, sim, acc.z);
        acc.w = fmaf(ub.w * ue.w, sim, acc.w);
    }

    // ---- combine the 4 user-subgroups (stride-16/32 butterfly) ----
    #pragma unroll
    for (int off = 16; off < 64; off <<= 1) {
        acc.x += __shfl_xor(acc.x, off);
        acc.y += __shfl_xor(acc.y, off);
        acc.z += __shfl_xor(acc.z, off);
        acc.w += __shfl_xor(acc.w, off);
    }
    if (uu == 0) red[wave][q] = acc;
    __syncthreads();

    // ---- combine the 4 waves; 16 lanes store 256B coalesced ----
    if (wave == 0 && uu == 0) {
        const float4 r0 = red[0][q], r1 = red[1][q], r2 = red[2][q], r3 = red[3][q];
        float4 o;
        o.x = r0.x + r1.x + r2.x + r3.x;
        o.y = r0.y + r1.y + r2.y + r3.y;
        o.z = r0.z + r1.z + r2.z + r3.z;
        o.w = r0.w + r1.w + r2.w + r3.w;
        *(float4*)(out + (size_t)g * D + 4 * q) = o;
    }
}

extern "C" void kernel_launch(void* const* d_in, const int* in_sizes, int n_in,
                              void* d_out, int out_size, void* d_ws, size_t ws_size,
                              hipStream_t stream) {
    const int*   group_user      = (const int*)  d_in[0];
    const int*   behavior_ids    = (const int*)  d_in[1];
    const float* behavior_counts = (const float*)d_in[2];
    const int*   target_user     = (const int*)  d_in[3];
    const float* similarity_vec  = (const float*)d_in[4];
    const float* user_emb_w      = (const float*)d_in[5];
    const float* item_emb_w      = (const float*)d_in[6];
    float*       out             = (float*)d_out;

    group_embedding_kernel<<<G, 256, 0, stream>>>(
        group_user, behavior_ids, behavior_counts, target_user,
        similarity_vec, user_emb_w, item_emb_w, out);
}

// Round 18
// 255.480 us; speedup vs baseline: 1.0655x; 1.0221x over previous
//
#include <hip/hip_runtime.h>
#include <hip/hip_bf16.h>

// GroupEmbedding — G=4096, U=50, M=20, D=S=64.
// R10 post-mortem: VGPR stayed 36 — hipcc's RP-minimizing scheduler sank the
// batched gathers back to their uses; the MLP experiment never ran. This
// round: force the batch with __builtin_amdgcn_sched_barrier(0) between the
// load cluster and the consume cluster (nothing may cross it, so regalloc
// must keep all 20 float4 gathers live -> ~320 lines in flight per wave).
// Verify via VGPR_Count >= 120. Predict dur 151 -> ~80-105us if latency x MLP
// bound; flat dur with high VGPR => structural service-rate limit.

constexpr int G = 4096;
constexpr int U = 50;
constexpr int M = 20;
constexpr int D = 64;
constexpr int S = 64;
constexpr int UPAD = 64;            // 4 waves * 4 subgroups * 4 iters
constexpr float FACTOR = 0.5f;

__global__ __launch_bounds__(256) void group_embedding_kernel(
    const int*   __restrict__ group_user,       // [G,U]
    const int*   __restrict__ behavior_ids,     // [G,U,M]
    const float* __restrict__ behavior_counts,  // [G,U,M]
    const int*   __restrict__ target_user,      // [G]
    const float* __restrict__ similarity_vec,   // [USER_NUM,S]
    const float* __restrict__ user_emb_w,       // [USER_NUM,D]
    const float* __restrict__ item_emb_w,       // [ITEM_NUM,D]
    float*       __restrict__ out)              // [G,D]
{
    const int g    = blockIdx.x;
    const int tid  = threadIdx.x;
    const int wave = tid >> 6;     // 0..3
    const int lane = tid & 63;
    const int uu   = lane >> 4;    // user subgroup 0..3
    const int q    = lane & 15;    // dim quad: dims 4q..4q+3

    __shared__ int    gu_lds[UPAD];
    __shared__ int    ids_lds[UPAD * M];
    __shared__ float  cnt_lds[UPAD * M];
    __shared__ float4 red[4][16];

    // ---- stage ids/counts/group_user into LDS (coalesced), zero-pad u>=U ----
    for (int i = tid; i < UPAD * M; i += 256) {
        const bool v = (i < U * M);
        ids_lds[i] = v ? behavior_ids   [(size_t)g * U * M + i] : 0;
        cnt_lds[i] = v ? behavior_counts[(size_t)g * U * M + i] : 0.0f;
    }
    if (tid < UPAD) gu_lds[tid] = (tid < U) ? group_user[g * U + tid] : 0;
    __syncthreads();

    const int tgt = target_user[g];
    const float4 tsim = *(const float4*)(similarity_vec + (size_t)tgt * S + 4 * q);

    float4 acc = {0.f, 0.f, 0.f, 0.f};

    #pragma unroll 1
    for (int iter = 0; iter < UPAD / 16; ++iter) {
        const int u  = iter * 16 + wave * 4 + uu;   // 0..63
        const int gu = gu_lds[u];

        // LDS reads up front so the VMEM issue burst is uninterrupted.
        int   ids [M];
        float cnts[M];
        #pragma unroll
        for (int m = 0; m < M; ++m) {
            ids [m] = ids_lds[u * M + m];
            cnts[m] = cnt_lds[u * M + m];
        }

        // ---- ISSUE all 22 gathers; fence pins them before any consume ----
        const float4 sv = *(const float4*)(similarity_vec + (size_t)gu * S + 4 * q);
        const float4 ue = *(const float4*)(user_emb_w     + (size_t)gu * D + 4 * q);
        float4 it[M];                       // 80 VGPRs, compile-time indexed
        #pragma unroll
        for (int m = 0; m < M; ++m)
            it[m] = *(const float4*)(item_emb_w + (size_t)ids[m] * D + 4 * q);

        __builtin_amdgcn_sched_barrier(0);  // nothing crosses: loads stay issued

        // ---- CONSUME: sim dot + shfl reduce first (item loads still in flight)
        float p = tsim.x * sv.x + tsim.y * sv.y + tsim.z * sv.z + tsim.w * sv.w;
        p += __shfl_xor(p, 1);
        p += __shfl_xor(p, 2);
        p += __shfl_xor(p, 4);
        p += __shfl_xor(p, 8);      // 64-elem dot within the 16-lane group
        const float sim = FACTOR * p;

        float4 ub = {0.f, 0.f, 0.f, 0.f};
        #pragma unroll
        for (int m = 0; m < M; ++m) {
            ub.x = fmaf(it[m].x, cnts[m], ub.x);
            ub.y = fmaf(it[m].y, cnts[m], ub.y);
            ub.z = fmaf(it[m].z, cnts[m], ub.z);
            ub.w = fmaf(it[m].w, cnts[m], ub.w);
        }

        acc.x = fmaf(ub.x * ue.x, sim, acc.x);
        acc.y = fmaf(ub.y * ue.y, sim, acc.y);
        acc.z = fmaf(ub.z * ue.z, sim, acc.z);
        acc.w = fmaf(ub.w * ue.w, sim, acc.w);
    }

    // ---- combine the 4 user-subgroups (stride-16/32 butterfly) ----
    #pragma unroll
    for (int off = 16; off < 64; off <<= 1) {
        acc.x += __shfl_xor(acc.x, off);
        acc.y += __shfl_xor(acc.y, off);
        acc.z += __shfl_xor(acc.z, off);
        acc.w += __shfl_xor(acc.w, off);
    }
    if (uu == 0) red[wave][q] = acc;
    __syncthreads();

    // ---- combine the 4 waves; 16 lanes store 256B coalesced ----
    if (wave == 0 && uu == 0) {
        const float4 r0 = red[0][q], r1 = red[1][q], r2 = red[2][q], r3 = red[3][q];
        float4 o;
        o.x = r0.x + r1.x + r2.x + r3.x;
        o.y = r0.y + r1.y + r2.y + r3.y;
        o.z = r0.z + r1.z + r2.z + r3.z;
        o.w = r0.w + r1.w + r2.w + r3.w;
        *(float4*)(out + (size_t)g * D + 4 * q) = o;
    }
}

extern "C" void kernel_launch(void* const* d_in, const int* in_sizes, int n_in,
                              void* d_out, int out_size, void* d_ws, size_t ws_size,
                              hipStream_t stream) {
    const int*   group_user      = (const int*)  d_in[0];
    const int*   behavior_ids    = (const int*)  d_in[1];
    const float* behavior_counts = (const float*)d_in[2];
    const int*   target_user     = (const int*)  d_in[3];
    const float* similarity_vec  = (const float*)d_in[4];
    const float* user_emb_w      = (const float*)d_in[5];
    const float* item_emb_w      = (const float*)d_in[6];
    float*       out             = (float*)d_out;

    group_embedding_kernel<<<G, 256, 0, stream>>>(
        group_user, behavior_ids, behavior_counts, target_user,
        similarity_vec, user_emb_w, item_emb_w, out);
}